// Round 14
// baseline (1260.352 us; speedup 1.0000x reference)
//
#include <hip/hip_runtime.h>
#include <hip/hip_bf16.h>

#define HID 64
#define RPW 16   // rows per wave in gemm2_reg
#define KCH 8    // k-chunk width (W regs live at a time = 2*KCH)

typedef __hip_bfloat16  bf16;
typedef __hip_bfloat162 bf162;
__device__ __forceinline__ float bl(bf16 h) { return __bfloat162float(h); }

// -------- fused dual GEMM, fp32 outputs (table production).
// waves_per_eu(8,8): VGPR_Count=40 in R13 -> fits 64-cap; 8 waves/EU hides
// the scalar-load/store latency that left R13 at 41% occupancy.
template <int KC>
__global__ __attribute__((amdgpu_flat_work_group_size(256, 256),
                          amdgpu_waves_per_eu(8, 8)))
void gemm2_reg(const float* in,
               const float* __restrict__ Wa, const float* __restrict__ Wb,
               float* outa, float* outb,
               int R, int ldw, int coloff) {
    int lane = threadIdx.x & 63;
    int wid = blockIdx.x * (blockDim.x >> 6) + (threadIdx.x >> 6);
    int j0 = __builtin_amdgcn_readfirstlane(wid * RPW);
    if (j0 >= R) return;
    float accx[RPW], accy[RPW];
#pragma unroll
    for (int r = 0; r < RPW; ++r) { accx[r] = 0.f; accy[r] = 0.f; }
    const float* pa = Wa + (size_t)lane * ldw + coloff;
    const float* pb = Wb + (size_t)lane * ldw + coloff;
#pragma unroll 1
    for (int kc = 0; kc < KC; kc += KCH) {
        float wx[KCH], wy[KCH];
#pragma unroll
        for (int kk = 0; kk < KCH; ++kk) { wx[kk] = pa[kc + kk]; wy[kk] = pb[kc + kk]; }
#pragma unroll
        for (int r = 0; r < RPW; ++r) {
            const float* rp = in + (size_t)(j0 + r) * KC + kc;
#pragma unroll
            for (int kk = 0; kk < KCH; ++kk) {
                float s = rp[kk];
                accx[r] = fmaf(s, wx[kk], accx[r]);
                accy[r] = fmaf(s, wy[kk], accy[r]);
            }
        }
    }
#pragma unroll
    for (int r = 0; r < RPW; ++r) {
        int j = j0 + r;
        outa[(size_t)j * HID + lane] = accx[r];
        outb[(size_t)j * HID + lane] = accy[r];
    }
}

// -------- same, but outb (the message operand) stored as bf16.
template <int KC>
__global__ __attribute__((amdgpu_flat_work_group_size(256, 256),
                          amdgpu_waves_per_eu(8, 8)))
void gemm2_regb(const float* in,
                const float* __restrict__ Wa, const float* __restrict__ Wb,
                float* outa, bf16* outb,
                int R, int ldw, int coloff) {
    int lane = threadIdx.x & 63;
    int wid = blockIdx.x * (blockDim.x >> 6) + (threadIdx.x >> 6);
    int j0 = __builtin_amdgcn_readfirstlane(wid * RPW);
    if (j0 >= R) return;
    float accx[RPW], accy[RPW];
#pragma unroll
    for (int r = 0; r < RPW; ++r) { accx[r] = 0.f; accy[r] = 0.f; }
    const float* pa = Wa + (size_t)lane * ldw + coloff;
    const float* pb = Wb + (size_t)lane * ldw + coloff;
#pragma unroll 1
    for (int kc = 0; kc < KC; kc += KCH) {
        float wx[KCH], wy[KCH];
#pragma unroll
        for (int kk = 0; kk < KCH; ++kk) { wx[kk] = pa[kc + kk]; wy[kk] = pb[kc + kk]; }
#pragma unroll
        for (int r = 0; r < RPW; ++r) {
            const float* rp = in + (size_t)(j0 + r) * KC + kc;
#pragma unroll
            for (int kk = 0; kk < KCH; ++kk) {
                float s = rp[kk];
                accx[r] = fmaf(s, wx[kk], accx[r]);
                accy[r] = fmaf(s, wy[kk], accy[r]);
            }
        }
    }
#pragma unroll
    for (int r = 0; r < RPW; ++r) {
        int j = j0 + r;
        outa[(size_t)j * HID + lane] = accx[r];
        outb[(size_t)j * HID + lane] = __float2bfloat16(accy[r]);
    }
}

// ======== batched CSR build (unchanged) ========
__global__ void zero4_k(int* p1, int s1, int* p2, int s2, int* p3, int s3,
                        int* p4, int s4, int nb1, int nb2, int nb3) {
    int b = blockIdx.x; int* p; int n; int lb;
    if (b < nb1)                 { p = p1; n = s1; lb = b; }
    else if (b < nb1 + nb2)      { p = p2; n = s2; lb = b - nb1; }
    else if (b < nb1 + nb2 + nb3){ p = p3; n = s3; lb = b - nb1 - nb2; }
    else                         { p = p4; n = s4; lb = b - nb1 - nb2 - nb3; }
    int i = lb * 256 + threadIdx.x;
    if (i < n) p[i] = 0;
}

__global__ void hist3_k(const int* e1, int E1, int* c1,
                        const int* e2, int E2, int* c2,
                        const int* e3, int E3, int* c3, int nb1, int nb2) {
    int b = blockIdx.x; const int* dst; int* c; int E; int lb;
    if (b < nb1)            { dst = e1 + E1; c = c1; E = E1; lb = b; }
    else if (b < nb1 + nb2) { dst = e2 + E2; c = c2; E = E2; lb = b - nb1; }
    else                    { dst = e3 + E3; c = c3; E = E3; lb = b - nb1 - nb2; }
    int e = lb * 256 + threadIdx.x;
    if (e < E) atomicAdd(&c[dst[e]], 1);
}

__device__ __forceinline__ void scan1_body(const int* __restrict__ cnt, int* __restrict__ rs,
                                           int* __restrict__ bsum, int n1, int n, int lb) {
    __shared__ int wsum[4];
    int t = threadIdx.x;
    int base = lb * 1024 + t * 4;
    int v[4]; int s = 0;
#pragma unroll
    for (int i = 0; i < 4; ++i) { int idx = base + i; v[i] = s; s += (idx < n) ? cnt[idx] : 0; }
    int lane = t & 63, wv = t >> 6;
    int x = s;
#pragma unroll
    for (int off = 1; off < 64; off <<= 1) { int y = __shfl_up(x, off, 64); if (lane >= off) x += y; }
    if (lane == 63) wsum[wv] = x;
    __syncthreads();
    int woff = 0;
    for (int w = 0; w < wv; ++w) woff += wsum[w];
    int excl = woff + (x - s);
#pragma unroll
    for (int i = 0; i < 4; ++i) { int idx = base + i; if (idx < n1) rs[idx] = excl + v[i]; }
    if (t == 255) bsum[lb] = wsum[0] + wsum[1] + wsum[2] + wsum[3];
}

__global__ void scan1_3k(const int* c1, int* r1, int* b1, int n1a, int na,
                         const int* c2, int* r2, int* b2, int n1b, int nb,
                         const int* c3, int* r3, int* b3, int n1c, int nc,
                         int nbl1, int nbl2) {
    int b = blockIdx.x;
    if (b < nbl1)             scan1_body(c1, r1, b1, n1a, na, b);
    else if (b < nbl1 + nbl2) scan1_body(c2, r2, b2, n1b, nb, b - nbl1);
    else                      scan1_body(c3, r3, b3, n1c, nc, b - nbl1 - nbl2);
}

__device__ __forceinline__ void scan2_body(int* bsum, int nb, int* wsum) {
    int t = threadIdx.x;
    int s = (t < nb) ? bsum[t] : 0;
    int lane = t & 63, wv = t >> 6;
    int x = s;
#pragma unroll
    for (int off = 1; off < 64; off <<= 1) { int y = __shfl_up(x, off, 64); if (lane >= off) x += y; }
    if (lane == 63) wsum[wv] = x;
    __syncthreads();
    int woff = 0;
    for (int w = 0; w < wv; ++w) woff += wsum[w];
    if (t < nb) bsum[t] = woff + x - s;
    __syncthreads();
}

__global__ void scan2_3k(int* b1, int nb1, int* b2, int nb2, int* b3, int nb3) {
    __shared__ int wsum[4];
    scan2_body(b1, nb1, wsum);
    scan2_body(b2, nb2, wsum);
    scan2_body(b3, nb3, wsum);
}

__global__ void scan3_3k(int* r1, const int* b1, int n1a,
                         int* r2, const int* b2, int n1b,
                         int* r3, const int* b3, int n1c, int nc1, int nc2) {
    int b = blockIdx.x; int* rs; const int* bsum; int n1; int lb;
    if (b < nc1)            { rs = r1; bsum = b1; n1 = n1a; lb = b; }
    else if (b < nc1 + nc2) { rs = r2; bsum = b2; n1 = n1b; lb = b - nc1; }
    else                    { rs = r3; bsum = b3; n1 = n1c; lb = b - nc1 - nc2; }
    int i = lb * 256 + threadIdx.x;
    if (i < n1) rs[i] += bsum[lb >> 2];
}

__global__ void fill3_k(const int* e1, int E1, const int* r1, int* c1, int* s1,
                        const int* e2, int E2, const int* r2, int* c2, int* s2,
                        const int* e3, int E3, const int* r3, int* c3, int* s3,
                        int nb1, int nb2) {
    int b = blockIdx.x;
    const int* edges; int E; const int* rs; int* cur; int* csrc; int lb;
    if (b < nb1)            { edges = e1; E = E1; rs = r1; cur = c1; csrc = s1; lb = b; }
    else if (b < nb1 + nb2) { edges = e2; E = E2; rs = r2; cur = c2; csrc = s2; lb = b - nb1; }
    else                    { edges = e3; E = E3; rs = r3; cur = c3; csrc = s3; lb = b - nb1 - nb2; }
    int e = lb * 256 + threadIdx.x;
    if (e >= E) return;
    int d = edges[E + e];
    int p = rs[d] + atomicAdd(&cur[d], 1);
    csrc[p] = edges[e];
}

// -------- gather + relu with bf16 messages (non-final layers)
__global__ void neighsum_relu_k(const int* __restrict__ rs, const int* __restrict__ csrc,
                                const bf162* __restrict__ m, float* __restrict__ z,
                                int R, int nb8) {
    int b = (int)(blockIdx.x & 7) * nb8 + (int)(blockIdx.x >> 3);
    int t = threadIdx.x;
    int wv = t >> 6, lane = t & 63;
    int j = b * 8 + wv * 2 + (lane >> 5);
    int f2 = lane & 31;
    if (j >= R) return;
    float2* z2p = (float2*)z;
    int s = rs[j], e = rs[j + 1];
    float2 a = z2p[(size_t)j * 32 + f2];
    float ax = a.x, ay = a.y;
    int k = s;
    for (; k + 8 <= e; k += 8) {
        int i0 = csrc[k],     i1 = csrc[k + 1], i2 = csrc[k + 2], i3 = csrc[k + 3];
        int i4 = csrc[k + 4], i5 = csrc[k + 5], i6 = csrc[k + 6], i7 = csrc[k + 7];
        bf162 v0 = m[(size_t)i0 * 32 + f2], v1 = m[(size_t)i1 * 32 + f2];
        bf162 v2 = m[(size_t)i2 * 32 + f2], v3 = m[(size_t)i3 * 32 + f2];
        bf162 v4 = m[(size_t)i4 * 32 + f2], v5 = m[(size_t)i5 * 32 + f2];
        bf162 v6 = m[(size_t)i6 * 32 + f2], v7 = m[(size_t)i7 * 32 + f2];
        ax += ((bl(v0.x) + bl(v1.x)) + (bl(v2.x) + bl(v3.x)))
            + ((bl(v4.x) + bl(v5.x)) + (bl(v6.x) + bl(v7.x)));
        ay += ((bl(v0.y) + bl(v1.y)) + (bl(v2.y) + bl(v3.y)))
            + ((bl(v4.y) + bl(v5.y)) + (bl(v6.y) + bl(v7.y)));
    }
    for (; k + 4 <= e; k += 4) {
        int i0 = csrc[k], i1 = csrc[k + 1], i2 = csrc[k + 2], i3 = csrc[k + 3];
        bf162 v0 = m[(size_t)i0 * 32 + f2], v1 = m[(size_t)i1 * 32 + f2];
        bf162 v2 = m[(size_t)i2 * 32 + f2], v3 = m[(size_t)i3 * 32 + f2];
        ax += (bl(v0.x) + bl(v1.x)) + (bl(v2.x) + bl(v3.x));
        ay += (bl(v0.y) + bl(v1.y)) + (bl(v2.y) + bl(v3.y));
    }
    for (; k < e; ++k) {
        bf162 v = m[(size_t)csrc[k] * 32 + f2];
        ax += bl(v.x); ay += bl(v.y);
    }
    z2p[(size_t)j * 32 + f2] = make_float2(fmaxf(ax, 0.f), fmaxf(ay, 0.f));
}

// -------- FINAL-layer gather + relu + segment-sum fused:
// relu(zinit[j] + sum m[...]) accumulated straight into comb (skip z write +
// segsum re-read: saves 74 MB round trip on level 3). Contention per comb
// address = rows-per-graph (1140 max) serialized fp32 atomics ≈ few µs.
__global__ void neighsum_segsum_k(const int* __restrict__ rs, const int* __restrict__ csrc,
                                  const bf162* __restrict__ m, const float* __restrict__ zinit,
                                  float* __restrict__ comb, int per, int coloff,
                                  int R, int nb8) {
    int b = (int)(blockIdx.x & 7) * nb8 + (int)(blockIdx.x >> 3);
    int t = threadIdx.x;
    int wv = t >> 6, lane = t & 63;
    int j = b * 8 + wv * 2 + (lane >> 5);
    int f2 = lane & 31;
    if (j >= R) return;
    const float2* z2p = (const float2*)zinit;
    int s = rs[j], e = rs[j + 1];
    float2 a = z2p[(size_t)j * 32 + f2];
    float ax = a.x, ay = a.y;
    int k = s;
    for (; k + 8 <= e; k += 8) {
        int i0 = csrc[k],     i1 = csrc[k + 1], i2 = csrc[k + 2], i3 = csrc[k + 3];
        int i4 = csrc[k + 4], i5 = csrc[k + 5], i6 = csrc[k + 6], i7 = csrc[k + 7];
        bf162 v0 = m[(size_t)i0 * 32 + f2], v1 = m[(size_t)i1 * 32 + f2];
        bf162 v2 = m[(size_t)i2 * 32 + f2], v3 = m[(size_t)i3 * 32 + f2];
        bf162 v4 = m[(size_t)i4 * 32 + f2], v5 = m[(size_t)i5 * 32 + f2];
        bf162 v6 = m[(size_t)i6 * 32 + f2], v7 = m[(size_t)i7 * 32 + f2];
        ax += ((bl(v0.x) + bl(v1.x)) + (bl(v2.x) + bl(v3.x)))
            + ((bl(v4.x) + bl(v5.x)) + (bl(v6.x) + bl(v7.x)));
        ay += ((bl(v0.y) + bl(v1.y)) + (bl(v2.y) + bl(v3.y)))
            + ((bl(v4.y) + bl(v5.y)) + (bl(v6.y) + bl(v7.y)));
    }
    for (; k + 4 <= e; k += 4) {
        int i0 = csrc[k], i1 = csrc[k + 1], i2 = csrc[k + 2], i3 = csrc[k + 3];
        bf162 v0 = m[(size_t)i0 * 32 + f2], v1 = m[(size_t)i1 * 32 + f2];
        bf162 v2 = m[(size_t)i2 * 32 + f2], v3 = m[(size_t)i3 * 32 + f2];
        ax += (bl(v0.x) + bl(v1.x)) + (bl(v2.x) + bl(v3.x));
        ay += (bl(v0.y) + bl(v1.y)) + (bl(v2.y) + bl(v3.y));
    }
    for (; k < e; ++k) {
        bf162 v = m[(size_t)csrc[k] * 32 + f2];
        ax += bl(v.x); ay += bl(v.y);
    }
    int g = j / per;
    float* cp = comb + (size_t)g * 192 + coloff + 2 * f2;
    atomicAdd(cp,     fmaxf(ax, 0.f));
    atomicAdd(cp + 1, fmaxf(ay, 0.f));
}

// -------- level-2 layer-0 combined gather: z-init (fp32) + m (bf16)
__global__ void gatherZM2_k(const float* __restrict__ hU1, const float* __restrict__ hV1,
                            const float* __restrict__ hU2, const float* __restrict__ hV2,
                            const int* __restrict__ gu, const int* __restrict__ gv,
                            const float* __restrict__ iso2,
                            const float* __restrict__ W1, const float* __restrict__ W2,
                            float* __restrict__ z, bf16* __restrict__ m,
                            int n2, int jstep) {
    int idx = blockIdx.x * 256 + threadIdx.x;
    int j = idx >> 6, f = idx & 63;
    float w1c = W1[f * 129 + 128], w2c = W2[f * 129 + 128];
#pragma unroll
    for (int r = 0; r < 4; ++r, j += jstep) {
        if (j >= n2) return;
        int u = gu[j], v = gv[j];
        float is = iso2[j];
        z[(size_t)j * HID + f] = hU1[u * HID + f] + hV1[v * HID + f] + is * w1c;
        m[(size_t)j * HID + f] =
            __float2bfloat16(hU2[u * HID + f] + hV2[v * HID + f] + is * w2c);
    }
}

// -------- level-3 layer-0 combined gather (iso3 one-hot x4)
__global__ void gatherZM3_k(const float* __restrict__ hA1, const float* __restrict__ hB1,
                            const float* __restrict__ hC1,
                            const float* __restrict__ hA2, const float* __restrict__ hB2,
                            const float* __restrict__ hC2,
                            const int* __restrict__ ga, const int* __restrict__ gb,
                            const int* __restrict__ gc, const float* __restrict__ iso3,
                            const float* __restrict__ W1, const float* __restrict__ W2,
                            float* __restrict__ z, bf16* __restrict__ m,
                            int n3, int jstep) {
    int idx = blockIdx.x * 256 + threadIdx.x;
    int j = idx >> 6, f = idx & 63;
    float w1c[4], w2c[4];
#pragma unroll
    for (int c = 0; c < 4; ++c) {
        w1c[c] = W1[f * 196 + 192 + c];
        w2c[c] = W2[f * 196 + 192 + c];
    }
    const float4* I4 = (const float4*)iso3;
#pragma unroll
    for (int r = 0; r < 4; ++r, j += jstep) {
        if (j >= n3) return;
        int a = ga[j], b = gb[j], c = gc[j];
        float4 iv = I4[j];
        float zz = hA1[a * HID + f] + hB1[b * HID + f] + hC1[c * HID + f]
                 + iv.x * w1c[0] + iv.y * w1c[1] + iv.z * w1c[2] + iv.w * w1c[3];
        float mm = hA2[a * HID + f] + hB2[b * HID + f] + hC2[c * HID + f]
                 + iv.x * w2c[0] + iv.y * w2c[1] + iv.z * w2c[2] + iv.w * w2c[3];
        z[(size_t)j * HID + f] = zz;
        m[(size_t)j * HID + f] = __float2bfloat16(mm);
    }
}

// -------- split segment sum (level 1 only now)
__global__ void segsum_split_k(const float* __restrict__ h, float* __restrict__ comb,
                               int per, int coloff, int S, int chunk) {
    int b = blockIdx.x;
    int g = b / S, s = b % S;
    int f = threadIdx.x;
    int r0 = s * chunk;
    int r1 = min(per, r0 + chunk);
    float acc = 0.f;
    const float* p = h + ((size_t)g * per + r0) * HID + f;
    for (int r = r0; r < r1; ++r) { acc += *p; p += HID; }
    atomicAdd(&comb[g * 192 + coloff + f], acc);
}

// -------- classifier
__global__ void classifier_k(const float* __restrict__ comb,
                             const float* __restrict__ cW1, const float* __restrict__ cb1,
                             const float* __restrict__ cW2, const float* __restrict__ cb2,
                             float* __restrict__ out) {
    __shared__ float row[192];
    __shared__ float hid[64];
    int g = blockIdx.x, t = threadIdx.x;
    for (int i = t; i < 192; i += 64) row[i] = comb[g * 192 + i];
    __syncthreads();
    float acc = cb1[t];
#pragma unroll 8
    for (int k = 0; k < 192; ++k) acc += row[k] * cW1[t * 192 + k];
    hid[t] = fmaxf(acc, 0.f);
    __syncthreads();
    if (t < 10) {
        float o = cb2[t];
#pragma unroll
        for (int k = 0; k < 64; ++k) o += hid[k] * cW2[t * 64 + k];
        out[g * 10 + t] = o;
    }
}

static inline int cdiv(long long a, long long b) { return (int)((a + b - 1) / b); }

extern "C" void kernel_launch(void* const* d_in, const int* in_sizes, int n_in,
                              void* d_out, int out_size, void* d_ws, size_t ws_size,
                              hipStream_t stream) {
    const float* x        = (const float*)d_in[0];
    const int*   eidx     = (const int*)d_in[1];
    const int*   gu2      = (const int*)d_in[3];
    const int*   gv2      = (const int*)d_in[4];
    const float* iso2     = (const float*)d_in[5];
    const int*   tedges   = (const int*)d_in[6];
    const int*   ga3      = (const int*)d_in[8];
    const int*   gb3      = (const int*)d_in[9];
    const int*   gc3      = (const int*)d_in[10];
    const float* iso3     = (const float*)d_in[11];
    const int*   hedges   = (const int*)d_in[12];
    const float* g1W1[3]  = {(const float*)d_in[14], (const float*)d_in[16], (const float*)d_in[18]};
    const float* g1W2[3]  = {(const float*)d_in[15], (const float*)d_in[17], (const float*)d_in[19]};
    const float* g2W1_0   = (const float*)d_in[20];
    const float* g2W2_0   = (const float*)d_in[21];
    const float* g2W1_1   = (const float*)d_in[22];
    const float* g2W2_1   = (const float*)d_in[23];
    const float* g3W1_0   = (const float*)d_in[24];
    const float* g3W2_0   = (const float*)d_in[25];
    const float* g3W1_1   = (const float*)d_in[26];
    const float* g3W2_1   = (const float*)d_in[27];
    const float* cW1      = (const float*)d_in[28];
    const float* cb1      = (const float*)d_in[29];
    const float* cW2      = (const float*)d_in[30];
    const float* cb2      = (const float*)d_in[31];
    float* out = (float*)d_out;

    const int N  = in_sizes[0] / 32;       // 2560
    const int E1 = in_sizes[1] / 2;
    const int n2 = in_sizes[3];            // 24320
    const int E2 = in_sizes[6] / 2;
    const int n3 = in_sizes[8];            // 145920
    const int E3 = in_sizes[12] / 2;
    const int G  = out_size / 10;          // 128
    const int per1 = N / G, per2 = n2 / G, per3 = n3 / G;

    // ---- workspace carve-up (float units)
    float* ws = (float*)d_ws;
    size_t off = 0;
    auto alloc = [&](size_t n) { float* p = ws + off; off += n; return p; };
    const size_t NH = (size_t)N * HID;
    float* nb0 = alloc(NH); float* nb1 = alloc(NH);
    bf16* mb1 = (bf16*)alloc(NH / 2 + 64);
    float* hU1 = alloc(NH); float* hV1 = alloc(NH); float* hU2 = alloc(NH); float* hV2 = alloc(NH);
    float* hA1 = alloc(NH); float* hB1 = alloc(NH); float* hC1 = alloc(NH);
    float* hA2 = alloc(NH); float* hB2 = alloc(NH); float* hC2 = alloc(NH);
    float* z2 = alloc((size_t)n2 * HID);
    bf16* m2b = (bf16*)alloc((size_t)n2 * HID / 2 + 64);
    float* z3 = alloc((size_t)n3 * HID);
    bf16* m3b = (bf16*)alloc((size_t)n3 * HID / 2 + 64);
    float* comb = alloc((size_t)G * 192);
    int* iws = (int*)(ws + off);
    size_t ioff = 0;
    auto ialloc = [&](size_t n) { int* p = iws + ioff; ioff += n; return p; };
    int* rs1 = ialloc(N + 1);  int* cur1 = ialloc(N);  int* csrc1 = ialloc(E1);
    int* rs2 = ialloc(n2 + 1); int* cur2 = ialloc(n2); int* csrc2 = ialloc(E2);
    int* rs3 = ialloc(n3 + 1); int* cur3 = ialloc(n3); int* csrc3 = ialloc(E3);
    int* bsum1 = ialloc(256); int* bsum2 = ialloc(256); int* bsum3 = ialloc(256);
    (void)ws_size;

    dim3 B256(256);
    auto gemm2 = [&](const float* in, const float* Wa, const float* Wb,
                     float* oa, float* ob, int R, int K, int ldw, int coloff) {
        int blocks = cdiv(cdiv(R, RPW), 4);
        if (K == 64)
            gemm2_reg<64><<<blocks, B256, 0, stream>>>(in, Wa, Wb, oa, ob, R, ldw, coloff);
        else
            gemm2_reg<32><<<blocks, B256, 0, stream>>>(in, Wa, Wb, oa, ob, R, ldw, coloff);
    };
    auto gemm2b = [&](const float* in, const float* Wa, const float* Wb,
                      float* oa, bf16* ob, int R, int K, int ldw, int coloff) {
        int blocks = cdiv(cdiv(R, RPW), 4);
        if (K == 64)
            gemm2_regb<64><<<blocks, B256, 0, stream>>>(in, Wa, Wb, oa, ob, R, ldw, coloff);
        else
            gemm2_regb<32><<<blocks, B256, 0, stream>>>(in, Wa, Wb, oa, ob, R, ldw, coloff);
    };
    auto neigh = [&](const int* rs, const int* csrc, const bf16* m, float* z, int R) {
        int nb = cdiv(R, 8);
        int nb8 = cdiv(nb, 8);
        neighsum_relu_k<<<nb8 * 8, B256, 0, stream>>>(rs, csrc, (const bf162*)m, z, R, nb8);
    };
    auto neigh_seg = [&](const int* rs, const int* csrc, const bf16* m, const float* zi,
                         int R, int per, int coloff) {
        int nb = cdiv(R, 8);
        int nb8 = cdiv(nb, 8);
        neighsum_segsum_k<<<nb8 * 8, B256, 0, stream>>>(
            rs, csrc, (const bf162*)m, zi, comb, per, coloff, R, nb8);
    };

    // ---- batched CSR build (7 dispatches; comb zero folded into first)
    int nz1 = cdiv(N, 256), nz2 = cdiv(n2, 256), nz3 = cdiv(n3, 256), nz4 = cdiv(G * 192, 256);
    zero4_k<<<nz1 + nz2 + nz3 + nz4, B256, 0, stream>>>(
        cur1, N, cur2, n2, cur3, n3, (int*)comb, G * 192, nz1, nz2, nz3);
    int ne1 = cdiv(E1, 256), ne2 = cdiv(E2, 256), ne3 = cdiv(E3, 256);
    hist3_k<<<ne1 + ne2 + ne3, B256, 0, stream>>>(
        eidx, E1, cur1, tedges, E2, cur2, hedges, E3, cur3, ne1, ne2);
    int ns1 = cdiv(N + 1, 1024), ns2 = cdiv(n2 + 1, 1024), ns3 = cdiv(n3 + 1, 1024);
    scan1_3k<<<ns1 + ns2 + ns3, B256, 0, stream>>>(
        cur1, rs1, bsum1, N + 1, N, cur2, rs2, bsum2, n2 + 1, n2,
        cur3, rs3, bsum3, n3 + 1, n3, ns1, ns2);
    scan2_3k<<<1, B256, 0, stream>>>(bsum1, ns1, bsum2, ns2, bsum3, ns3);
    int nc1 = cdiv(N + 1, 256), nc2 = cdiv(n2 + 1, 256), nc3 = cdiv(n3 + 1, 256);
    scan3_3k<<<nc1 + nc2 + nc3, B256, 0, stream>>>(
        rs1, bsum1, N + 1, rs2, bsum2, n2 + 1, rs3, bsum3, n3 + 1, nc1, nc2);
    zero4_k<<<nz1 + nz2 + nz3, B256, 0, stream>>>(
        cur1, N, cur2, n2, cur3, n3, nullptr, 0, nz1, nz2, nz3);
    fill3_k<<<ne1 + ne2 + ne3, B256, 0, stream>>>(
        eidx, E1, rs1, cur1, csrc1, tedges, E2, rs2, cur2, csrc2,
        hedges, E3, rs3, cur3, csrc3, ne1, ne2);

    // ================= level 1: node GNN (3 layers; bf16 messages) ==========
    const float* hcur = x;
    float* zb[2] = {nb0, nb1};
    for (int l = 0; l < 3; ++l) {
        int K = (l == 0) ? 32 : 64;
        float* z = zb[l & 1];
        gemm2b(hcur, g1W1[l], g1W2[l], z, mb1, N, K, K, 0);
        neigh(rs1, csrc1, mb1, z, N);
        hcur = z;
    }
    const float* h = hcur;   // = nb0 after 3 layers

    {
        int chunk = 64;
        int S = cdiv(per1, chunk);
        segsum_split_k<<<G * S, 64, 0, stream>>>(h, comb, per1, 0, S, chunk);
    }

    // ================= level 2: pair GNN (2 layers) =================
    gemm2(h, g2W1_0, g2W2_0, hU1, hU2, N, 64, 129, 0);
    gemm2(h, g2W1_0, g2W2_0, hV1, hV2, N, 64, 129, 64);
    {
        int jstep = cdiv(n2, 4);
        gatherZM2_k<<<cdiv((long long)jstep * 64, 256), B256, 0, stream>>>(
            hU1, hV1, hU2, hV2, gu2, gv2, iso2, g2W1_0, g2W2_0, z2, m2b, n2, jstep);
    }
    neigh(rs2, csrc2, m2b, z2, n2);
    gemm2b(z2, g2W1_1, g2W2_1, z2, m2b, n2, 64, 64, 0);   // in-place z2
    neigh_seg(rs2, csrc2, m2b, z2, n2, per2, 64);         // fused final+segsum

    // ================= level 3: triple GNN (2 layers) =================
    gemm2(h, g3W1_0, g3W2_0, hA1, hA2, N, 64, 196, 0);
    gemm2(h, g3W1_0, g3W2_0, hB1, hB2, N, 64, 196, 64);
    gemm2(h, g3W1_0, g3W2_0, hC1, hC2, N, 64, 196, 128);
    {
        int jstep = cdiv(n3, 4);
        gatherZM3_k<<<cdiv((long long)jstep * 64, 256), B256, 0, stream>>>(
            hA1, hB1, hC1, hA2, hB2, hC2, ga3, gb3, gc3, iso3,
            g3W1_0, g3W2_0, z3, m3b, n3, jstep);
    }
    neigh(rs3, csrc3, m3b, z3, n3);
    gemm2b(z3, g3W1_1, g3W2_1, z3, m3b, n3, 64, 64, 0);   // in-place z3
    neigh_seg(rs3, csrc3, m3b, z3, n3, per3, 128);        // fused final+segsum

    // ================= classifier =================
    classifier_k<<<G, 64, 0, stream>>>(comb, cW1, cb1, cW2, cb2, out);
}

// Round 15
// 538.267 us; speedup vs baseline: 2.3415x; 2.3415x over previous
//
#include <hip/hip_runtime.h>
#include <hip/hip_bf16.h>

#define HID 64
#define RPW 16   // rows per wave in gemm2_reg
#define KCH 8    // k-chunk width (W regs live at a time = 2*KCH)

typedef __hip_bfloat16  bf16;
typedef __hip_bfloat162 bf162;
__device__ __forceinline__ float bl(bf16 h) { return __bfloat162float(h); }

// -------- fused dual GEMM, fp32 outputs (table production).
// waves_per_eu(8,8): VGPR_Count=40 at (6,6) in R13 -> fits the 64 cap.
// (R14's neighsum_segsum fusion is REVERTED: line-granular atomic
// serialization on comb made it 740us — G12: reduce before atomics.)
template <int KC>
__global__ __attribute__((amdgpu_flat_work_group_size(256, 256),
                          amdgpu_waves_per_eu(8, 8)))
void gemm2_reg(const float* in,
               const float* __restrict__ Wa, const float* __restrict__ Wb,
               float* outa, float* outb,
               int R, int ldw, int coloff) {
    int lane = threadIdx.x & 63;
    int wid = blockIdx.x * (blockDim.x >> 6) + (threadIdx.x >> 6);
    int j0 = __builtin_amdgcn_readfirstlane(wid * RPW);
    if (j0 >= R) return;
    float accx[RPW], accy[RPW];
#pragma unroll
    for (int r = 0; r < RPW; ++r) { accx[r] = 0.f; accy[r] = 0.f; }
    const float* pa = Wa + (size_t)lane * ldw + coloff;
    const float* pb = Wb + (size_t)lane * ldw + coloff;
#pragma unroll 1
    for (int kc = 0; kc < KC; kc += KCH) {
        float wx[KCH], wy[KCH];
#pragma unroll
        for (int kk = 0; kk < KCH; ++kk) { wx[kk] = pa[kc + kk]; wy[kk] = pb[kc + kk]; }
#pragma unroll
        for (int r = 0; r < RPW; ++r) {
            const float* rp = in + (size_t)(j0 + r) * KC + kc;
#pragma unroll
            for (int kk = 0; kk < KCH; ++kk) {
                float s = rp[kk];
                accx[r] = fmaf(s, wx[kk], accx[r]);
                accy[r] = fmaf(s, wy[kk], accy[r]);
            }
        }
    }
#pragma unroll
    for (int r = 0; r < RPW; ++r) {
        int j = j0 + r;
        outa[(size_t)j * HID + lane] = accx[r];
        outb[(size_t)j * HID + lane] = accy[r];
    }
}

// -------- same, but outb (the message operand) stored as bf16.
template <int KC>
__global__ __attribute__((amdgpu_flat_work_group_size(256, 256),
                          amdgpu_waves_per_eu(8, 8)))
void gemm2_regb(const float* in,
                const float* __restrict__ Wa, const float* __restrict__ Wb,
                float* outa, bf16* outb,
                int R, int ldw, int coloff) {
    int lane = threadIdx.x & 63;
    int wid = blockIdx.x * (blockDim.x >> 6) + (threadIdx.x >> 6);
    int j0 = __builtin_amdgcn_readfirstlane(wid * RPW);
    if (j0 >= R) return;
    float accx[RPW], accy[RPW];
#pragma unroll
    for (int r = 0; r < RPW; ++r) { accx[r] = 0.f; accy[r] = 0.f; }
    const float* pa = Wa + (size_t)lane * ldw + coloff;
    const float* pb = Wb + (size_t)lane * ldw + coloff;
#pragma unroll 1
    for (int kc = 0; kc < KC; kc += KCH) {
        float wx[KCH], wy[KCH];
#pragma unroll
        for (int kk = 0; kk < KCH; ++kk) { wx[kk] = pa[kc + kk]; wy[kk] = pb[kc + kk]; }
#pragma unroll
        for (int r = 0; r < RPW; ++r) {
            const float* rp = in + (size_t)(j0 + r) * KC + kc;
#pragma unroll
            for (int kk = 0; kk < KCH; ++kk) {
                float s = rp[kk];
                accx[r] = fmaf(s, wx[kk], accx[r]);
                accy[r] = fmaf(s, wy[kk], accy[r]);
            }
        }
    }
#pragma unroll
    for (int r = 0; r < RPW; ++r) {
        int j = j0 + r;
        outa[(size_t)j * HID + lane] = accx[r];
        outb[(size_t)j * HID + lane] = __float2bfloat16(accy[r]);
    }
}

// ======== batched CSR build (unchanged) ========
__global__ void zero4_k(int* p1, int s1, int* p2, int s2, int* p3, int s3,
                        int* p4, int s4, int nb1, int nb2, int nb3) {
    int b = blockIdx.x; int* p; int n; int lb;
    if (b < nb1)                 { p = p1; n = s1; lb = b; }
    else if (b < nb1 + nb2)      { p = p2; n = s2; lb = b - nb1; }
    else if (b < nb1 + nb2 + nb3){ p = p3; n = s3; lb = b - nb1 - nb2; }
    else                         { p = p4; n = s4; lb = b - nb1 - nb2 - nb3; }
    int i = lb * 256 + threadIdx.x;
    if (i < n) p[i] = 0;
}

__global__ void hist3_k(const int* e1, int E1, int* c1,
                        const int* e2, int E2, int* c2,
                        const int* e3, int E3, int* c3, int nb1, int nb2) {
    int b = blockIdx.x; const int* dst; int* c; int E; int lb;
    if (b < nb1)            { dst = e1 + E1; c = c1; E = E1; lb = b; }
    else if (b < nb1 + nb2) { dst = e2 + E2; c = c2; E = E2; lb = b - nb1; }
    else                    { dst = e3 + E3; c = c3; E = E3; lb = b - nb1 - nb2; }
    int e = lb * 256 + threadIdx.x;
    if (e < E) atomicAdd(&c[dst[e]], 1);
}

__device__ __forceinline__ void scan1_body(const int* __restrict__ cnt, int* __restrict__ rs,
                                           int* __restrict__ bsum, int n1, int n, int lb) {
    __shared__ int wsum[4];
    int t = threadIdx.x;
    int base = lb * 1024 + t * 4;
    int v[4]; int s = 0;
#pragma unroll
    for (int i = 0; i < 4; ++i) { int idx = base + i; v[i] = s; s += (idx < n) ? cnt[idx] : 0; }
    int lane = t & 63, wv = t >> 6;
    int x = s;
#pragma unroll
    for (int off = 1; off < 64; off <<= 1) { int y = __shfl_up(x, off, 64); if (lane >= off) x += y; }
    if (lane == 63) wsum[wv] = x;
    __syncthreads();
    int woff = 0;
    for (int w = 0; w < wv; ++w) woff += wsum[w];
    int excl = woff + (x - s);
#pragma unroll
    for (int i = 0; i < 4; ++i) { int idx = base + i; if (idx < n1) rs[idx] = excl + v[i]; }
    if (t == 255) bsum[lb] = wsum[0] + wsum[1] + wsum[2] + wsum[3];
}

__global__ void scan1_3k(const int* c1, int* r1, int* b1, int n1a, int na,
                         const int* c2, int* r2, int* b2, int n1b, int nb,
                         const int* c3, int* r3, int* b3, int n1c, int nc,
                         int nbl1, int nbl2) {
    int b = blockIdx.x;
    if (b < nbl1)             scan1_body(c1, r1, b1, n1a, na, b);
    else if (b < nbl1 + nbl2) scan1_body(c2, r2, b2, n1b, nb, b - nbl1);
    else                      scan1_body(c3, r3, b3, n1c, nc, b - nbl1 - nbl2);
}

__device__ __forceinline__ void scan2_body(int* bsum, int nb, int* wsum) {
    int t = threadIdx.x;
    int s = (t < nb) ? bsum[t] : 0;
    int lane = t & 63, wv = t >> 6;
    int x = s;
#pragma unroll
    for (int off = 1; off < 64; off <<= 1) { int y = __shfl_up(x, off, 64); if (lane >= off) x += y; }
    if (lane == 63) wsum[wv] = x;
    __syncthreads();
    int woff = 0;
    for (int w = 0; w < wv; ++w) woff += wsum[w];
    if (t < nb) bsum[t] = woff + x - s;
    __syncthreads();
}

__global__ void scan2_3k(int* b1, int nb1, int* b2, int nb2, int* b3, int nb3) {
    __shared__ int wsum[4];
    scan2_body(b1, nb1, wsum);
    scan2_body(b2, nb2, wsum);
    scan2_body(b3, nb3, wsum);
}

__global__ void scan3_3k(int* r1, const int* b1, int n1a,
                         int* r2, const int* b2, int n1b,
                         int* r3, const int* b3, int n1c, int nc1, int nc2) {
    int b = blockIdx.x; int* rs; const int* bsum; int n1; int lb;
    if (b < nc1)            { rs = r1; bsum = b1; n1 = n1a; lb = b; }
    else if (b < nc1 + nc2) { rs = r2; bsum = b2; n1 = n1b; lb = b - nc1; }
    else                    { rs = r3; bsum = b3; n1 = n1c; lb = b - nc1 - nc2; }
    int i = lb * 256 + threadIdx.x;
    if (i < n1) rs[i] += bsum[lb >> 2];
}

__global__ void fill3_k(const int* e1, int E1, const int* r1, int* c1, int* s1,
                        const int* e2, int E2, const int* r2, int* c2, int* s2,
                        const int* e3, int E3, const int* r3, int* c3, int* s3,
                        int nb1, int nb2) {
    int b = blockIdx.x;
    const int* edges; int E; const int* rs; int* cur; int* csrc; int lb;
    if (b < nb1)            { edges = e1; E = E1; rs = r1; cur = c1; csrc = s1; lb = b; }
    else if (b < nb1 + nb2) { edges = e2; E = E2; rs = r2; cur = c2; csrc = s2; lb = b - nb1; }
    else                    { edges = e3; E = E3; rs = r3; cur = c3; csrc = s3; lb = b - nb1 - nb2; }
    int e = lb * 256 + threadIdx.x;
    if (e >= E) return;
    int d = edges[E + e];
    int p = rs[d] + atomicAdd(&cur[d], 1);
    csrc[p] = edges[e];
}

// -------- gather + relu with bf16 messages
__global__ void neighsum_relu_k(const int* __restrict__ rs, const int* __restrict__ csrc,
                                const bf162* __restrict__ m, float* __restrict__ z,
                                int R, int nb8) {
    int b = (int)(blockIdx.x & 7) * nb8 + (int)(blockIdx.x >> 3);
    int t = threadIdx.x;
    int wv = t >> 6, lane = t & 63;
    int j = b * 8 + wv * 2 + (lane >> 5);
    int f2 = lane & 31;
    if (j >= R) return;
    float2* z2p = (float2*)z;
    int s = rs[j], e = rs[j + 1];
    float2 a = z2p[(size_t)j * 32 + f2];
    float ax = a.x, ay = a.y;
    int k = s;
    for (; k + 8 <= e; k += 8) {
        int i0 = csrc[k],     i1 = csrc[k + 1], i2 = csrc[k + 2], i3 = csrc[k + 3];
        int i4 = csrc[k + 4], i5 = csrc[k + 5], i6 = csrc[k + 6], i7 = csrc[k + 7];
        bf162 v0 = m[(size_t)i0 * 32 + f2], v1 = m[(size_t)i1 * 32 + f2];
        bf162 v2 = m[(size_t)i2 * 32 + f2], v3 = m[(size_t)i3 * 32 + f2];
        bf162 v4 = m[(size_t)i4 * 32 + f2], v5 = m[(size_t)i5 * 32 + f2];
        bf162 v6 = m[(size_t)i6 * 32 + f2], v7 = m[(size_t)i7 * 32 + f2];
        ax += ((bl(v0.x) + bl(v1.x)) + (bl(v2.x) + bl(v3.x)))
            + ((bl(v4.x) + bl(v5.x)) + (bl(v6.x) + bl(v7.x)));
        ay += ((bl(v0.y) + bl(v1.y)) + (bl(v2.y) + bl(v3.y)))
            + ((bl(v4.y) + bl(v5.y)) + (bl(v6.y) + bl(v7.y)));
    }
    for (; k + 4 <= e; k += 4) {
        int i0 = csrc[k], i1 = csrc[k + 1], i2 = csrc[k + 2], i3 = csrc[k + 3];
        bf162 v0 = m[(size_t)i0 * 32 + f2], v1 = m[(size_t)i1 * 32 + f2];
        bf162 v2 = m[(size_t)i2 * 32 + f2], v3 = m[(size_t)i3 * 32 + f2];
        ax += (bl(v0.x) + bl(v1.x)) + (bl(v2.x) + bl(v3.x));
        ay += (bl(v0.y) + bl(v1.y)) + (bl(v2.y) + bl(v3.y));
    }
    for (; k < e; ++k) {
        bf162 v = m[(size_t)csrc[k] * 32 + f2];
        ax += bl(v.x); ay += bl(v.y);
    }
    z2p[(size_t)j * 32 + f2] = make_float2(fmaxf(ax, 0.f), fmaxf(ay, 0.f));
}

// -------- level-2 layer-0 combined gather: z-init (fp32) + m (bf16)
__global__ void gatherZM2_k(const float* __restrict__ hU1, const float* __restrict__ hV1,
                            const float* __restrict__ hU2, const float* __restrict__ hV2,
                            const int* __restrict__ gu, const int* __restrict__ gv,
                            const float* __restrict__ iso2,
                            const float* __restrict__ W1, const float* __restrict__ W2,
                            float* __restrict__ z, bf16* __restrict__ m,
                            int n2, int jstep) {
    int idx = blockIdx.x * 256 + threadIdx.x;
    int j = idx >> 6, f = idx & 63;
    float w1c = W1[f * 129 + 128], w2c = W2[f * 129 + 128];
#pragma unroll
    for (int r = 0; r < 4; ++r, j += jstep) {
        if (j >= n2) return;
        int u = gu[j], v = gv[j];
        float is = iso2[j];
        z[(size_t)j * HID + f] = hU1[u * HID + f] + hV1[v * HID + f] + is * w1c;
        m[(size_t)j * HID + f] =
            __float2bfloat16(hU2[u * HID + f] + hV2[v * HID + f] + is * w2c);
    }
}

// -------- level-3 layer-0 combined gather (iso3 one-hot x4)
__global__ void gatherZM3_k(const float* __restrict__ hA1, const float* __restrict__ hB1,
                            const float* __restrict__ hC1,
                            const float* __restrict__ hA2, const float* __restrict__ hB2,
                            const float* __restrict__ hC2,
                            const int* __restrict__ ga, const int* __restrict__ gb,
                            const int* __restrict__ gc, const float* __restrict__ iso3,
                            const float* __restrict__ W1, const float* __restrict__ W2,
                            float* __restrict__ z, bf16* __restrict__ m,
                            int n3, int jstep) {
    int idx = blockIdx.x * 256 + threadIdx.x;
    int j = idx >> 6, f = idx & 63;
    float w1c[4], w2c[4];
#pragma unroll
    for (int c = 0; c < 4; ++c) {
        w1c[c] = W1[f * 196 + 192 + c];
        w2c[c] = W2[f * 196 + 192 + c];
    }
    const float4* I4 = (const float4*)iso3;
#pragma unroll
    for (int r = 0; r < 4; ++r, j += jstep) {
        if (j >= n3) return;
        int a = ga[j], b = gb[j], c = gc[j];
        float4 iv = I4[j];
        float zz = hA1[a * HID + f] + hB1[b * HID + f] + hC1[c * HID + f]
                 + iv.x * w1c[0] + iv.y * w1c[1] + iv.z * w1c[2] + iv.w * w1c[3];
        float mm = hA2[a * HID + f] + hB2[b * HID + f] + hC2[c * HID + f]
                 + iv.x * w2c[0] + iv.y * w2c[1] + iv.z * w2c[2] + iv.w * w2c[3];
        z[(size_t)j * HID + f] = zz;
        m[(size_t)j * HID + f] = __float2bfloat16(mm);
    }
}

// -------- split segment sum
__global__ void segsum_split_k(const float* __restrict__ h, float* __restrict__ comb,
                               int per, int coloff, int S, int chunk) {
    int b = blockIdx.x;
    int g = b / S, s = b % S;
    int f = threadIdx.x;
    int r0 = s * chunk;
    int r1 = min(per, r0 + chunk);
    float acc = 0.f;
    const float* p = h + ((size_t)g * per + r0) * HID + f;
    for (int r = r0; r < r1; ++r) { acc += *p; p += HID; }
    atomicAdd(&comb[g * 192 + coloff + f], acc);
}

// -------- classifier
__global__ void classifier_k(const float* __restrict__ comb,
                             const float* __restrict__ cW1, const float* __restrict__ cb1,
                             const float* __restrict__ cW2, const float* __restrict__ cb2,
                             float* __restrict__ out) {
    __shared__ float row[192];
    __shared__ float hid[64];
    int g = blockIdx.x, t = threadIdx.x;
    for (int i = t; i < 192; i += 64) row[i] = comb[g * 192 + i];
    __syncthreads();
    float acc = cb1[t];
#pragma unroll 8
    for (int k = 0; k < 192; ++k) acc += row[k] * cW1[t * 192 + k];
    hid[t] = fmaxf(acc, 0.f);
    __syncthreads();
    if (t < 10) {
        float o = cb2[t];
#pragma unroll
        for (int k = 0; k < 64; ++k) o += hid[k] * cW2[t * 64 + k];
        out[g * 10 + t] = o;
    }
}

static inline int cdiv(long long a, long long b) { return (int)((a + b - 1) / b); }

extern "C" void kernel_launch(void* const* d_in, const int* in_sizes, int n_in,
                              void* d_out, int out_size, void* d_ws, size_t ws_size,
                              hipStream_t stream) {
    const float* x        = (const float*)d_in[0];
    const int*   eidx     = (const int*)d_in[1];
    const int*   gu2      = (const int*)d_in[3];
    const int*   gv2      = (const int*)d_in[4];
    const float* iso2     = (const float*)d_in[5];
    const int*   tedges   = (const int*)d_in[6];
    const int*   ga3      = (const int*)d_in[8];
    const int*   gb3      = (const int*)d_in[9];
    const int*   gc3      = (const int*)d_in[10];
    const float* iso3     = (const float*)d_in[11];
    const int*   hedges   = (const int*)d_in[12];
    const float* g1W1[3]  = {(const float*)d_in[14], (const float*)d_in[16], (const float*)d_in[18]};
    const float* g1W2[3]  = {(const float*)d_in[15], (const float*)d_in[17], (const float*)d_in[19]};
    const float* g2W1_0   = (const float*)d_in[20];
    const float* g2W2_0   = (const float*)d_in[21];
    const float* g2W1_1   = (const float*)d_in[22];
    const float* g2W2_1   = (const float*)d_in[23];
    const float* g3W1_0   = (const float*)d_in[24];
    const float* g3W2_0   = (const float*)d_in[25];
    const float* g3W1_1   = (const float*)d_in[26];
    const float* g3W2_1   = (const float*)d_in[27];
    const float* cW1      = (const float*)d_in[28];
    const float* cb1      = (const float*)d_in[29];
    const float* cW2      = (const float*)d_in[30];
    const float* cb2      = (const float*)d_in[31];
    float* out = (float*)d_out;

    const int N  = in_sizes[0] / 32;       // 2560
    const int E1 = in_sizes[1] / 2;
    const int n2 = in_sizes[3];            // 24320
    const int E2 = in_sizes[6] / 2;
    const int n3 = in_sizes[8];            // 145920
    const int E3 = in_sizes[12] / 2;
    const int G  = out_size / 10;          // 128
    const int per1 = N / G, per2 = n2 / G, per3 = n3 / G;

    // ---- workspace carve-up (float units)
    float* ws = (float*)d_ws;
    size_t off = 0;
    auto alloc = [&](size_t n) { float* p = ws + off; off += n; return p; };
    const size_t NH = (size_t)N * HID;
    float* nb0 = alloc(NH); float* nb1 = alloc(NH);
    bf16* mb1 = (bf16*)alloc(NH / 2 + 64);
    float* hU1 = alloc(NH); float* hV1 = alloc(NH); float* hU2 = alloc(NH); float* hV2 = alloc(NH);
    float* hA1 = alloc(NH); float* hB1 = alloc(NH); float* hC1 = alloc(NH);
    float* hA2 = alloc(NH); float* hB2 = alloc(NH); float* hC2 = alloc(NH);
    float* z2 = alloc((size_t)n2 * HID);
    bf16* m2b = (bf16*)alloc((size_t)n2 * HID / 2 + 64);
    float* z3 = alloc((size_t)n3 * HID);
    bf16* m3b = (bf16*)alloc((size_t)n3 * HID / 2 + 64);
    float* comb = alloc((size_t)G * 192);
    int* iws = (int*)(ws + off);
    size_t ioff = 0;
    auto ialloc = [&](size_t n) { int* p = iws + ioff; ioff += n; return p; };
    int* rs1 = ialloc(N + 1);  int* cur1 = ialloc(N);  int* csrc1 = ialloc(E1);
    int* rs2 = ialloc(n2 + 1); int* cur2 = ialloc(n2); int* csrc2 = ialloc(E2);
    int* rs3 = ialloc(n3 + 1); int* cur3 = ialloc(n3); int* csrc3 = ialloc(E3);
    int* bsum1 = ialloc(256); int* bsum2 = ialloc(256); int* bsum3 = ialloc(256);
    (void)ws_size;

    dim3 B256(256);
    auto gemm2 = [&](const float* in, const float* Wa, const float* Wb,
                     float* oa, float* ob, int R, int K, int ldw, int coloff) {
        int blocks = cdiv(cdiv(R, RPW), 4);
        if (K == 64)
            gemm2_reg<64><<<blocks, B256, 0, stream>>>(in, Wa, Wb, oa, ob, R, ldw, coloff);
        else
            gemm2_reg<32><<<blocks, B256, 0, stream>>>(in, Wa, Wb, oa, ob, R, ldw, coloff);
    };
    auto gemm2b = [&](const float* in, const float* Wa, const float* Wb,
                      float* oa, bf16* ob, int R, int K, int ldw, int coloff) {
        int blocks = cdiv(cdiv(R, RPW), 4);
        if (K == 64)
            gemm2_regb<64><<<blocks, B256, 0, stream>>>(in, Wa, Wb, oa, ob, R, ldw, coloff);
        else
            gemm2_regb<32><<<blocks, B256, 0, stream>>>(in, Wa, Wb, oa, ob, R, ldw, coloff);
    };
    auto neigh = [&](const int* rs, const int* csrc, const bf16* m, float* z, int R) {
        int nb = cdiv(R, 8);
        int nb8 = cdiv(nb, 8);
        neighsum_relu_k<<<nb8 * 8, B256, 0, stream>>>(rs, csrc, (const bf162*)m, z, R, nb8);
    };
    auto segsum = [&](const float* h, int per, int coloff) {
        int chunk = 64;
        int S = cdiv(per, chunk);
        segsum_split_k<<<G * S, 64, 0, stream>>>(h, comb, per, coloff, S, chunk);
    };

    // ---- batched CSR build (7 dispatches; comb zero folded into first)
    int nz1 = cdiv(N, 256), nz2 = cdiv(n2, 256), nz3 = cdiv(n3, 256), nz4 = cdiv(G * 192, 256);
    zero4_k<<<nz1 + nz2 + nz3 + nz4, B256, 0, stream>>>(
        cur1, N, cur2, n2, cur3, n3, (int*)comb, G * 192, nz1, nz2, nz3);
    int ne1 = cdiv(E1, 256), ne2 = cdiv(E2, 256), ne3 = cdiv(E3, 256);
    hist3_k<<<ne1 + ne2 + ne3, B256, 0, stream>>>(
        eidx, E1, cur1, tedges, E2, cur2, hedges, E3, cur3, ne1, ne2);
    int ns1 = cdiv(N + 1, 1024), ns2 = cdiv(n2 + 1, 1024), ns3 = cdiv(n3 + 1, 1024);
    scan1_3k<<<ns1 + ns2 + ns3, B256, 0, stream>>>(
        cur1, rs1, bsum1, N + 1, N, cur2, rs2, bsum2, n2 + 1, n2,
        cur3, rs3, bsum3, n3 + 1, n3, ns1, ns2);
    scan2_3k<<<1, B256, 0, stream>>>(bsum1, ns1, bsum2, ns2, bsum3, ns3);
    int nc1 = cdiv(N + 1, 256), nc2 = cdiv(n2 + 1, 256), nc3 = cdiv(n3 + 1, 256);
    scan3_3k<<<nc1 + nc2 + nc3, B256, 0, stream>>>(
        rs1, bsum1, N + 1, rs2, bsum2, n2 + 1, rs3, bsum3, n3 + 1, nc1, nc2);
    zero4_k<<<nz1 + nz2 + nz3, B256, 0, stream>>>(
        cur1, N, cur2, n2, cur3, n3, nullptr, 0, nz1, nz2, nz3);
    fill3_k<<<ne1 + ne2 + ne3, B256, 0, stream>>>(
        eidx, E1, rs1, cur1, csrc1, tedges, E2, rs2, cur2, csrc2,
        hedges, E3, rs3, cur3, csrc3, ne1, ne2);

    // ================= level 1: node GNN (3 layers; bf16 messages) ==========
    const float* hcur = x;
    float* zb[2] = {nb0, nb1};
    for (int l = 0; l < 3; ++l) {
        int K = (l == 0) ? 32 : 64;
        float* z = zb[l & 1];
        gemm2b(hcur, g1W1[l], g1W2[l], z, mb1, N, K, K, 0);
        neigh(rs1, csrc1, mb1, z, N);
        hcur = z;
    }
    const float* h = hcur;   // = nb0 after 3 layers

    segsum(h, per1, 0);

    // ================= level 2: pair GNN (2 layers) =================
    gemm2(h, g2W1_0, g2W2_0, hU1, hU2, N, 64, 129, 0);
    gemm2(h, g2W1_0, g2W2_0, hV1, hV2, N, 64, 129, 64);
    {
        int jstep = cdiv(n2, 4);
        gatherZM2_k<<<cdiv((long long)jstep * 64, 256), B256, 0, stream>>>(
            hU1, hV1, hU2, hV2, gu2, gv2, iso2, g2W1_0, g2W2_0, z2, m2b, n2, jstep);
    }
    neigh(rs2, csrc2, m2b, z2, n2);
    gemm2b(z2, g2W1_1, g2W2_1, z2, m2b, n2, 64, 64, 0);   // in-place z2
    neigh(rs2, csrc2, m2b, z2, n2);
    segsum(z2, per2, 64);

    // ================= level 3: triple GNN (2 layers) =================
    gemm2(h, g3W1_0, g3W2_0, hA1, hA2, N, 64, 196, 0);
    gemm2(h, g3W1_0, g3W2_0, hB1, hB2, N, 64, 196, 64);
    gemm2(h, g3W1_0, g3W2_0, hC1, hC2, N, 64, 196, 128);
    {
        int jstep = cdiv(n3, 4);
        gatherZM3_k<<<cdiv((long long)jstep * 64, 256), B256, 0, stream>>>(
            hA1, hB1, hC1, hA2, hB2, hC2, ga3, gb3, gc3, iso3,
            g3W1_0, g3W2_0, z3, m3b, n3, jstep);
    }
    neigh(rs3, csrc3, m3b, z3, n3);
    gemm2b(z3, g3W1_1, g3W2_1, z3, m3b, n3, 64, 64, 0);   // in-place z3
    neigh(rs3, csrc3, m3b, z3, n3);
    segsum(z3, per3, 128);

    // ================= classifier =================
    classifier_k<<<G, 64, 0, stream>>>(comb, cW1, cb1, cW2, cb2, out);
}